// Round 2
// baseline (203.887 us; speedup 1.0000x reference)
//
#include <hip/hip_runtime.h>

// EMA energy normalizer: mag [B,F,T] fp32 -> (mag_norm [B,F,T], mag_mean [B,1,T])
//   frame_means = mean over F; EMA scan over T (m = .99*m + .01*fm, init running_mean);
//   mag_norm = mag / (m + bias + 1e-8)
//
// Structure: K1 row-streaming partial F-sums (register accumulators, contiguous
// reads) -> K2 per-batch parallel affine scan -> K3 row-per-block normalize
// (mag re-read expected to hit Infinity Cache).

#define B_  32
#define F_  257
#define T_  3000
#define T4  750       // T/4 float4s per row
#define NCH 16        // F-dimension chunks; grid K1 = B*NCH = 512 blocks
#define MOM 0.99f
#define OMM 0.01f
#define EPS_ 1e-8f

// ---------------------------------------------------------------------------
// K1: block = (b, c). Streams rows f in [f0,f1) of batch b fully contiguously
// (12 KB per row); each thread accumulates 3 fixed t4-slots in registers.
// part layout: [B][NCH][T] floats. One coalesced float4 write per slot.
// ---------------------------------------------------------------------------
__global__ __launch_bounds__(256) void k1_rowsum(const float* __restrict__ mag,
                                                 float* __restrict__ part) {
    const int blk = blockIdx.x;       // b*NCH + c  (consecutive blocks = adjacent f-chunks)
    const int b   = blk >> 4;
    const int c   = blk & (NCH - 1);
    const int f0  = (c * F_) / NCH;
    const int f1  = ((c + 1) * F_) / NCH;
    const int tid = threadIdx.x;
    const float4* magv = reinterpret_cast<const float4*>(mag);

    float4 a0 = make_float4(0.f, 0.f, 0.f, 0.f);
    float4 a1 = a0, a2 = a0;
    const bool has2 = tid < (T4 - 512);   // slots: tid, tid+256, tid+512(<750)

    int base = (b * F_ + f0) * T4;
    for (int f = f0; f < f1; ++f, base += T4) {
        float4 v0 = magv[base + tid];
        float4 v1 = magv[base + tid + 256];
        a0.x += v0.x; a0.y += v0.y; a0.z += v0.z; a0.w += v0.w;
        a1.x += v1.x; a1.y += v1.y; a1.z += v1.z; a1.w += v1.w;
        if (has2) {
            float4 v2 = magv[base + tid + 512];
            a2.x += v2.x; a2.y += v2.y; a2.z += v2.z; a2.w += v2.w;
        }
    }
    float4* pv = reinterpret_cast<float4*>(part);
    pv[blk * T4 + tid]       = a0;
    pv[blk * T4 + tid + 256] = a1;
    if (has2) pv[blk * T4 + tid + 512] = a2;
}

// ---------------------------------------------------------------------------
// K2: one block per batch b. Reduce NCH partials -> frame means in LDS,
// chunked parallel scan of affine recurrence (Hillis-Steele over (A,B) maps),
// replay into LDS, then coalesced dump of mag_mean and recip.
// ---------------------------------------------------------------------------
__global__ __launch_bounds__(256) void k2_scan(const float* __restrict__ part,
                                               const float* __restrict__ bias,
                                               const float* __restrict__ rmean,
                                               float* __restrict__ mag_mean,
                                               float* __restrict__ recip) {
    __shared__ float xs[T_];
    __shared__ float sA[256];
    __shared__ float sB[256];
    const int b = blockIdx.x;
    const int tid = threadIdx.x;

    // frame means for this b (part is [B][NCH][T]: contiguous 48000 floats per b)
    for (int t = tid; t < T_; t += 256) {
        float s = 0.f;
        #pragma unroll
        for (int c = 0; c < NCH; ++c) s += part[(b * NCH + c) * T_ + t];
        xs[t] = s * (1.0f / F_);
    }
    __syncthreads();

    // local chunk scan: 250 active threads x 12 steps = 3000
    const int CH = 12;
    const int t0 = tid * CH;
    float A = 1.f, Bv = 0.f;
    if (t0 < T_) {
        #pragma unroll
        for (int j = 0; j < CH; ++j) {
            float x = xs[t0 + j];
            Bv = MOM * Bv + OMM * x;
            A *= MOM;
        }
    }
    sA[tid] = A; sB[tid] = Bv;
    __syncthreads();

    // Hillis-Steele inclusive scan; compose (prev) then (cur):
    // (Ap,Bp)∘(Ac,Bc) -> (Ap*Ac, Bp*Ac + Bc)
    for (int off = 1; off < 256; off <<= 1) {
        float cA = sA[tid], cB = sB[tid];
        float pA = 1.f, pB = 0.f;
        if (tid >= off) { pA = sA[tid - off]; pB = sB[tid - off]; }
        __syncthreads();
        if (tid >= off) { sA[tid] = pA * cA; sB[tid] = pB * cA + cB; }
        __syncthreads();
    }

    // exclusive prefix = inclusive of tid-1
    float pA = 1.f, pB = 0.f;
    if (tid > 0) { pA = sA[tid - 1]; pB = sB[tid - 1]; }
    __syncthreads();

    const float bias0 = bias[0];
    if (t0 < T_) {
        float m = pA * rmean[0] + pB;   // m_{t0-1}
        #pragma unroll
        for (int j = 0; j < CH; ++j) {
            float x = xs[t0 + j];
            m = MOM * m + OMM * x;
            xs[t0 + j] = m + bias0;     // stash mean+bias
        }
    }
    __syncthreads();

    // coalesced dump
    for (int t = tid; t < T_; t += 256) {
        float mb = xs[t];
        mag_mean[b * T_ + t] = mb;
        recip[b * T_ + t]    = 1.0f / (mb + EPS_);
    }
}

// ---------------------------------------------------------------------------
// K3: one block per (b,f) row. out = mag * recip[b][t]; 3 float4/thread,
// fully coalesced; recip row is L2-resident.
// ---------------------------------------------------------------------------
__global__ __launch_bounds__(256) void k3_norm(const float* __restrict__ mag,
                                               const float* __restrict__ recip,
                                               float* __restrict__ out) {
    const int r   = blockIdx.x;       // b*F_ + f
    const int b   = r / F_;           // one divide per block (magic mul)
    const int tid = threadIdx.x;
    const float4* magv = reinterpret_cast<const float4*>(mag);
    const float4* rv   = reinterpret_cast<const float4*>(recip);
    float4* ov         = reinterpret_cast<float4*>(out);
    const int base  = r * T4;
    const int rbase = b * T4;

    float4 v0 = magv[base + tid];
    float4 r0 = rv[rbase + tid];
    float4 v1 = magv[base + tid + 256];
    float4 r1 = rv[rbase + tid + 256];
    float4 o;
    o.x = v0.x * r0.x; o.y = v0.y * r0.y; o.z = v0.z * r0.z; o.w = v0.w * r0.w;
    ov[base + tid] = o;
    o.x = v1.x * r1.x; o.y = v1.y * r1.y; o.z = v1.z * r1.z; o.w = v1.w * r1.w;
    ov[base + tid + 256] = o;
    if (tid < T4 - 512) {
        float4 v2 = magv[base + tid + 512];
        float4 r2 = rv[rbase + tid + 512];
        o.x = v2.x * r2.x; o.y = v2.y * r2.y; o.z = v2.z * r2.z; o.w = v2.w * r2.w;
        ov[base + tid + 512] = o;
    }
}

extern "C" void kernel_launch(void* const* d_in, const int* in_sizes, int n_in,
                              void* d_out, int out_size, void* d_ws, size_t ws_size,
                              hipStream_t stream) {
    const float* mag   = (const float*)d_in[0];
    const float* bias  = (const float*)d_in[1];
    const float* rmean = (const float*)d_in[2];
    float* out      = (float*)d_out;
    float* mag_mean = out + (size_t)B_ * F_ * T_;     // second tuple output
    float* part  = (float*)d_ws;                      // B*NCH*T floats = 6.1 MB
    float* recip = part + (size_t)B_ * NCH * T_;      // B*T floats = 384 KB

    k1_rowsum<<<B_ * NCH, 256, 0, stream>>>(mag, part);
    k2_scan<<<B_, 256, 0, stream>>>(part, bias, rmean, mag_mean, recip);
    k3_norm<<<B_ * F_, 256, 0, stream>>>(mag, recip, out);
}